// Round 13
// baseline (35.140 us; speedup 1.0000x reference)
//
#include <hip/hip_runtime.h>
#include <math.h>

#define B_ 512
#define I_ 512
#define O_ 512
#define BO_ (B_*O_)

// fast path (kanU): block = 128b x 32o x 32i (2 chunks), thread = 8b x 2o
#define ZU 16                  // i-splits (grid = 4 bt x 16 ot x 16 iz = 1024)

// legacy kanZ fallback tiling
#define TB 64
#define TO 16
#define KI 16
#define ZN 8
#define NIZ (I_/ZN)
#define NCHZ (NIZ/KI)
#define LXS (TB + 4)

#define SQH    0.84932180028801904f   // sqrt(0.5*log2(e))
#define MN_   (-1.2023679775792928f)  // -(2 ln2) * NORM
#define NN_   (-0.86732507058407750f) // -NORM
#define BN_EPS (1e-5f)

#if defined(__has_builtin)
#if __has_builtin(__builtin_amdgcn_exp2f)
#define EXP2F(v) __builtin_amdgcn_exp2f(v)
#endif
#endif
#ifndef EXP2F
#define EXP2F(v) exp2f(v)
#endif

// ---------------------------------------------------------------------------
// K1: partial KAN sums. Block = 128b x 32o x 32i; thread = 8b x 2o.
// LDS per ii: 2 param quads (k-planes; 16 lanes read contiguous 256B = free)
// + 2 x quads (4-address broadcast) = 4 ds_read_b128 / 16 evals = 4 B/eval.
// kanV's proven staging discipline: loads issued BEFORE the barrier, derive
// with short live ranges, 2 barriers/chunk, no launch-bounds cap (no spill).
// Staging split: threads 0-127 params, 128-255 x-transpose.
// Grid 1024 = 4 blocks/CU = 16 waves/CU. XCD k owns o in [64k,64k+64).
// ---------------------------------------------------------------------------
__global__ __launch_bounds__(256) void kanU(
    const float* __restrict__ x, const float* __restrict__ scale,
    const float* __restrict__ bias, const float* __restrict__ weight,
    float* __restrict__ pY)
{
    __shared__ float4 Lp[16][2][16];   // [i][k][oq] {c,g,m,n}   8 KB
    __shared__ float  Lx[16][128];     // [i][b]                  8 KB

    const int fid = blockIdx.x;
    const int xcd = fid & 7;
    const int seq = fid >> 3;              // 0..127
    const int otl = seq & 1;               // 2 o-subtiles per XCD
    const int bt  = (seq >> 1) & 3;        // 4 b-tiles of 128
    const int iz  = seq >> 3;              // 0..15

    const int o0 = (xcd * 2 + otl) * 32;   // XCD k owns o [64k, 64k+64)
    const int b0 = bt * 128;
    const int z0 = iz * 32;

    const int t  = threadIdx.x;
    const int oq = t & 15;                 // eval o-pair (o = o0 + oq*2 + k)
    const int bq = t >> 4;                 // eval b-octet (b = b0 + bq*8 + r)

    // staging roles
    const int isP = (t < 128);             // params vs x
    const int pi  = t >> 3;                // param i-row 0..15   (t<128)
    const int pq  = t & 7;                 // param o-quad 0..7   (t<128)
    const int tx  = t - 128;               // x b-row 0..127      (t>=128)

    float4 aA0 = {0,0,0,0}, aB0 = {0,0,0,0};   // k=0: b-quads A,B
    float4 aA1 = {0,0,0,0}, aB1 = {0,0,0,0};   // k=1

    for (int ch = 0; ch < 2; ++ch) {
        const int i0 = z0 + ch * 16;

        // ---- issue global loads BEFORE the barrier ----
        float4 s4, b4, w4, xv0, xv1, xv2, xv3;
        if (isP) {
            const size_t g = (size_t)(i0 + pi) * O_ + o0 + pq * 4;
            s4 = *reinterpret_cast<const float4*>(&scale[g]);
            b4 = *reinterpret_cast<const float4*>(&bias[g]);
            w4 = *reinterpret_cast<const float4*>(&weight[g]);
        } else {
            const size_t xg = (size_t)(b0 + tx) * I_ + i0;
            xv0 = *reinterpret_cast<const float4*>(&x[xg + 0]);
            xv1 = *reinterpret_cast<const float4*>(&x[xg + 4]);
            xv2 = *reinterpret_cast<const float4*>(&x[xg + 8]);
            xv3 = *reinterpret_cast<const float4*>(&x[xg + 12]);
        }

        __syncthreads();               // previous chunk fully consumed

        if (isP) {
            // derive {c, g, m, n}; o_local = pq*4 + j -> plane k = o&1, slot oq = o>>1
            {
                const float c = SQH * __builtin_amdgcn_rcpf(s4.x);
                const int ol = pq * 4 + 0;
                Lp[pi][ol & 1][ol >> 1] = make_float4(c, -b4.x * c, MN_ * w4.x, NN_ * w4.x);
            }
            {
                const float c = SQH * __builtin_amdgcn_rcpf(s4.y);
                const int ol = pq * 4 + 1;
                Lp[pi][ol & 1][ol >> 1] = make_float4(c, -b4.y * c, MN_ * w4.y, NN_ * w4.y);
            }
            {
                const float c = SQH * __builtin_amdgcn_rcpf(s4.z);
                const int ol = pq * 4 + 2;
                Lp[pi][ol & 1][ol >> 1] = make_float4(c, -b4.z * c, MN_ * w4.z, NN_ * w4.z);
            }
            {
                const float c = SQH * __builtin_amdgcn_rcpf(s4.w);
                const int ol = pq * 4 + 3;
                Lp[pi][ol & 1][ol >> 1] = make_float4(c, -b4.w * c, MN_ * w4.w, NN_ * w4.w);
            }
        } else {
            Lx[ 0][tx] = xv0.x;  Lx[ 1][tx] = xv0.y;
            Lx[ 2][tx] = xv0.z;  Lx[ 3][tx] = xv0.w;
            Lx[ 4][tx] = xv1.x;  Lx[ 5][tx] = xv1.y;
            Lx[ 6][tx] = xv1.z;  Lx[ 7][tx] = xv1.w;
            Lx[ 8][tx] = xv2.x;  Lx[ 9][tx] = xv2.y;
            Lx[10][tx] = xv2.z;  Lx[11][tx] = xv2.w;
            Lx[12][tx] = xv3.x;  Lx[13][tx] = xv3.y;
            Lx[14][tx] = xv3.z;  Lx[15][tx] = xv3.w;
        }

        __syncthreads();               // staging visible

#define EV2(xs, A0, A1)                                                      \
    {                                                                        \
        { const float h  = fmaf((xs), p0.x, p0.y);                           \
          const float un = -h * h;                                           \
          const float e  = EXP2F(un);                                        \
          const float gg = fmaf(un, p0.z, p0.w);                             \
          (A0) = fmaf(gg, e, (A0)); }                                        \
        { const float h  = fmaf((xs), p1.x, p1.y);                           \
          const float un = -h * h;                                           \
          const float e  = EXP2F(un);                                        \
          const float gg = fmaf(un, p1.z, p1.w);                             \
          (A1) = fmaf(gg, e, (A1)); }                                        \
    }

        #pragma unroll 4
        for (int ii = 0; ii < 16; ++ii) {
            const float4 p0 = Lp[ii][0][oq];   // 16 lanes: contiguous 256B
            const float4 p1 = Lp[ii][1][oq];
            const float4 xA = *reinterpret_cast<const float4*>(&Lx[ii][bq * 8 + 0]);
            const float4 xB = *reinterpret_cast<const float4*>(&Lx[ii][bq * 8 + 4]);
            EV2(xA.x, aA0.x, aA1.x);
            EV2(xA.y, aA0.y, aA1.y);
            EV2(xA.z, aA0.z, aA1.z);
            EV2(xA.w, aA0.w, aA1.w);
            EV2(xB.x, aB0.x, aB1.x);
            EV2(xB.y, aB0.y, aB1.y);
            EV2(xB.z, aB0.z, aB1.z);
            EV2(xB.w, aB0.w, aB1.w);
        }
#undef EV2
    }

    // store: per b-row, the thread's o-pair (o0+oq*2, +1) is a contiguous float2
    {
        const size_t rb = ((size_t)iz * B_ + b0 + bq * 8) * O_ + o0 + oq * 2;
        *reinterpret_cast<float2*>(&pY[rb + 0 * O_]) = make_float2(aA0.x, aA1.x);
        *reinterpret_cast<float2*>(&pY[rb + 1 * O_]) = make_float2(aA0.y, aA1.y);
        *reinterpret_cast<float2*>(&pY[rb + 2 * O_]) = make_float2(aA0.z, aA1.z);
        *reinterpret_cast<float2*>(&pY[rb + 3 * O_]) = make_float2(aA0.w, aA1.w);
        *reinterpret_cast<float2*>(&pY[rb + 4 * O_]) = make_float2(aB0.x, aB1.x);
        *reinterpret_cast<float2*>(&pY[rb + 5 * O_]) = make_float2(aB0.y, aB1.y);
        *reinterpret_cast<float2*>(&pY[rb + 6 * O_]) = make_float2(aB0.z, aB1.z);
        *reinterpret_cast<float2*>(&pY[rb + 7 * O_]) = make_float2(aB0.w, aB1.w);
    }
}

// ---------------------------------------------------------------------------
// kanZ (proven R7 kernel) — fallback for small workspace (needs 8 MB).
// ---------------------------------------------------------------------------
__global__ __launch_bounds__(256) void kanZ(
    const float* __restrict__ x, const float* __restrict__ scale,
    const float* __restrict__ bias, const float* __restrict__ weight,
    float* __restrict__ pY)
{
    __shared__ float Lx[KI][LXS];
    __shared__ float Lp[KI][TO][4];

    const int fid = blockIdx.x;
    const int xcd = fid & 7;
    const int seq = fid >> 3;
    const int ot  = xcd * 4 + (seq & 3);
    const int by  = (seq >> 2) & 7;
    const int iz  = seq >> 5;

    const int o0 = ot * TO;
    const int b0 = by * TB;
    const int z0 = iz * NIZ;

    const int t   = threadIdx.x;
    const int to  = t & (TO - 1);
    const int tb4 = t >> 4;
    const int lb  = t >> 2;
    const int lq  = t & 3;
    const int li  = t >> 4;
    const int lo  = t & 15;

    float acc0 = 0.f, acc1 = 0.f, acc2 = 0.f, acc3 = 0.f;

    for (int ch = 0; ch < NCHZ; ++ch) {
        const int i0 = z0 + ch * KI;
        const float4 xv = *reinterpret_cast<const float4*>(
            &x[(size_t)(b0 + lb) * I_ + i0 + lq * 4]);
        const int pidx = (i0 + li) * O_ + o0 + lo;
        const float sc = scale[pidx];
        const float bi = bias[pidx];
        const float w  = weight[pidx];

        __syncthreads();
        Lx[lq * 4 + 0][lb] = xv.x;
        Lx[lq * 4 + 1][lb] = xv.y;
        Lx[lq * 4 + 2][lb] = xv.z;
        Lx[lq * 4 + 3][lb] = xv.w;
        const float c = SQH * __builtin_amdgcn_rcpf(sc);
        Lp[li][lo][0] = c;
        Lp[li][lo][1] = -bi * c;
        Lp[li][lo][2] = MN_ * w;
        Lp[li][lo][3] = NN_ * w;
        __syncthreads();

        #pragma unroll
        for (int ii = 0; ii < KI; ++ii) {
            const float4 p  = *reinterpret_cast<const float4*>(&Lp[ii][to][0]);
            const float4 x4 = *reinterpret_cast<const float4*>(&Lx[ii][tb4 * 4]);
            {
                const float h  = fmaf(x4.x, p.x, p.y);
                const float un = -h * h;
                const float e  = EXP2F(un);
                const float gg = fmaf(un, p.z, p.w);
                acc0 = fmaf(gg, e, acc0);
            }
            {
                const float h  = fmaf(x4.y, p.x, p.y);
                const float un = -h * h;
                const float e  = EXP2F(un);
                const float gg = fmaf(un, p.z, p.w);
                acc1 = fmaf(gg, e, acc1);
            }
            {
                const float h  = fmaf(x4.z, p.x, p.y);
                const float un = -h * h;
                const float e  = EXP2F(un);
                const float gg = fmaf(un, p.z, p.w);
                acc2 = fmaf(gg, e, acc2);
            }
            {
                const float h  = fmaf(x4.w, p.x, p.y);
                const float un = -h * h;
                const float e  = EXP2F(un);
                const float gg = fmaf(un, p.z, p.w);
                acc3 = fmaf(gg, e, acc3);
            }
        }
    }

    const size_t base = ((size_t)iz * B_ + b0 + tb4 * 4) * O_ + o0 + to;
    pY[base + 0 * O_] = acc0;
    pY[base + 1 * O_] = acc1;
    pY[base + 2 * O_] = acc2;
    pY[base + 3 * O_] = acc3;
}

// ---------------------------------------------------------------------------
// K2: fused NZ-partial combine + BatchNorm stats + apply. 128 blocks, 4 o's
// each; o<->XCD mapping matches the producer so pY reads hit the local L2.
// ---------------------------------------------------------------------------
template <int NZ>
__global__ __launch_bounds__(256) void comb_bn(
    const float* __restrict__ pY,
    const float* __restrict__ gamma, const float* __restrict__ beta,
    float* __restrict__ y)
{
    __shared__ float Ws[4][8];
    __shared__ float Ac[8];

    const int bid = blockIdx.x;                       // 0..127
    const int o4  = (bid & 7) * 64 + (bid >> 3) * 4;  // XCD k owns o [64k,64k+64)
    const int t   = threadIdx.x;

    float4 v[2];
    float sx = 0.f, sy = 0.f, sz = 0.f, sw = 0.f;
    float qx = 0.f, qy = 0.f, qz = 0.f, qw = 0.f;
    #pragma unroll
    for (int r = 0; r < 2; ++r) {
        const int b = t + 256 * r;
        const size_t base = (size_t)b * O_ + o4;
        float4 a = *reinterpret_cast<const float4*>(&pY[base]);
        #pragma unroll
        for (int z = 1; z < NZ; ++z) {
            const float4 p = *reinterpret_cast<const float4*>(&pY[(size_t)z * BO_ + base]);
            a.x += p.x; a.y += p.y; a.z += p.z; a.w += p.w;
        }
        v[r] = a;
        sx += a.x; sy += a.y; sz += a.z; sw += a.w;
        qx += a.x * a.x; qy += a.y * a.y; qz += a.z * a.z; qw += a.w * a.w;
    }

    #pragma unroll
    for (int m = 1; m < 64; m <<= 1) {
        sx += __shfl_xor(sx, m); sy += __shfl_xor(sy, m);
        sz += __shfl_xor(sz, m); sw += __shfl_xor(sw, m);
        qx += __shfl_xor(qx, m); qy += __shfl_xor(qy, m);
        qz += __shfl_xor(qz, m); qw += __shfl_xor(qw, m);
    }
    if ((t & 63) == 0) {
        const int wv = t >> 6;
        Ws[wv][0] = sx; Ws[wv][1] = sy; Ws[wv][2] = sz; Ws[wv][3] = sw;
        Ws[wv][4] = qx; Ws[wv][5] = qy; Ws[wv][6] = qz; Ws[wv][7] = qw;
    }
    __syncthreads();
    if (t < 4) {
        const float s  = Ws[0][t]     + Ws[1][t]     + Ws[2][t]     + Ws[3][t];
        const float q  = Ws[0][t + 4] + Ws[1][t + 4] + Ws[2][t + 4] + Ws[3][t + 4];
        const float mean = s * (1.0f / B_);
        const float var  = q * (1.0f / B_) - mean * mean;
        const float inv  = rsqrtf(var + BN_EPS);
        const float a = gamma[o4 + t] * inv;
        Ac[t]     = a;
        Ac[t + 4] = fmaf(-mean, a, beta[o4 + t]);
    }
    __syncthreads();

    const float4 a4 = *reinterpret_cast<const float4*>(&Ac[0]);
    const float4 c4 = *reinterpret_cast<const float4*>(&Ac[4]);
    #pragma unroll
    for (int r = 0; r < 2; ++r) {
        const int b = t + 256 * r;
        float4 o;
        o.x = fmaf(v[r].x, a4.x, c4.x);
        o.y = fmaf(v[r].y, a4.y, c4.y);
        o.z = fmaf(v[r].z, a4.z, c4.z);
        o.w = fmaf(v[r].w, a4.w, c4.w);
        *reinterpret_cast<float4*>(&y[(size_t)b * O_ + o4]) = o;
    }
}

// ---------------------------------------------------------------------------

extern "C" void kernel_launch(void* const* d_in, const int* in_sizes, int n_in,
                              void* d_out, int out_size, void* d_ws, size_t ws_size,
                              hipStream_t stream) {
    const float* x      = (const float*)d_in[0];
    const float* scale  = (const float*)d_in[1];
    const float* bias   = (const float*)d_in[2];
    const float* weight = (const float*)d_in[3];
    const float* gamma  = (const float*)d_in[4];
    const float* beta   = (const float*)d_in[5];
    float* out = (float*)d_out;

    const size_t pYU_b = (size_t)ZU * BO_ * sizeof(float);    // 16 MB
    const size_t pYZ_b = (size_t)ZN * BO_ * sizeof(float);    // 8 MB

    if (ws_size >= pYU_b) {
        float* pY = (float*)d_ws;
        kanU<<<8 * 2 * 4 * ZU, 256, 0, stream>>>(x, scale, bias, weight, pY); // 1024 blocks
        comb_bn<ZU><<<O_ / 4, 256, 0, stream>>>(pY, gamma, beta, out);        // 128 blocks
    } else if (ws_size >= pYZ_b) {
        float* pY = (float*)d_ws;
        kanZ<<<32 * 8 * 8, 256, 0, stream>>>(x, scale, bias, weight, pY);
        comb_bn<ZN><<<O_ / 4, 256, 0, stream>>>(pY, gamma, beta, out);
    }
}